// Round 1
// baseline (7259.656 us; speedup 1.0000x reference)
//
#include <hip/hip_runtime.h>
#include <stdint.h>

typedef _Float16 f16;
typedef _Float16 f16x8 __attribute__((ext_vector_type(8)));
typedef float f32x4 __attribute__((ext_vector_type(4)));

#define BATCH 256
#define SEQ   128
#define EMB   300
#define HID   1024
#define OUTD  20
#define CAT   1324          // HID + EMB
#define KE    1344          // padded K: 1024 (c) + 320 (x-part incl. bias-1 and zero pad)
#define XP    320           // xe row: 300 emb + [300]=1.0 (bias) + zeros

__device__ __forceinline__ float sigm(float z)  { return 1.f / (1.f + __expf(-z)); }
__device__ __forceinline__ float tanhf_(float z){ float e = __expf(2.f * z); return 1.f - 2.f / (e + 1.f); }

// ---------------------------------------------------------------------------
// Weight packing: Wru_e[2048][1344] f16  (rows 0..1023 = W_r|b_r, 1024..2047 = W_u|b_u)
//                 Wc_e [1024][1344] f16, Wp_e[32][1024] f16 (rows >=20 zero)
// ---------------------------------------------------------------------------
__global__ void pack_kernel(const float* __restrict__ Wr, const float* __restrict__ br,
                            const float* __restrict__ Wu, const float* __restrict__ bu,
                            const float* __restrict__ Wc, const float* __restrict__ bc,
                            const float* __restrict__ Wp,
                            f16* __restrict__ Wru_e, f16* __restrict__ Wc_e, f16* __restrict__ Wp_e)
{
    const int NRU = 2048 * KE, NC = 1024 * KE, NP = 32 * HID;
    for (int idx = blockIdx.x * blockDim.x + threadIdx.x; idx < NRU + NC + NP;
         idx += gridDim.x * blockDim.x) {
        if (idx < NRU) {
            int n = idx / KE, k = idx - n * KE;
            const float* Ws = (n < HID) ? Wr : Wu;
            const float* bs = (n < HID) ? br : bu;
            int row = n & (HID - 1);
            float v = (k < CAT) ? Ws[(size_t)row * CAT + k] : ((k == CAT) ? bs[row] : 0.f);
            Wru_e[idx] = (f16)v;
        } else if (idx < NRU + NC) {
            int j = idx - NRU;
            int n = j / KE, k = j - n * KE;
            float v = (k < CAT) ? Wc[(size_t)n * CAT + k] : ((k == CAT) ? bc[n] : 0.f);
            Wc_e[j] = (f16)v;
        } else {
            int j = idx - NRU - NC;
            int n = j / HID, k = j & (HID - 1);
            Wp_e[j] = (n < OUTD) ? (f16)Wp[(size_t)n * HID + k] : (f16)(0.f);
        }
    }
}

// ---------------------------------------------------------------------------
// Embedding gather: xe[t][b][0..319] f16 : emb row, then 1.0 at [300], zeros
// ---------------------------------------------------------------------------
__global__ void gather_kernel(const int* __restrict__ x, const float* __restrict__ emb,
                              f16* __restrict__ xe)
{
    const int TOT = SEQ * BATCH * XP;
    for (int idx = blockIdx.x * blockDim.x + threadIdx.x; idx < TOT;
         idx += gridDim.x * blockDim.x) {
        int e  = idx % XP;
        int rb = idx / XP;            // t*256 + b
        int b  = rb & 255, t = rb >> 8;
        float v;
        if (e < EMB) { int id = x[b * SEQ + t]; v = emb[(size_t)id * EMB + e]; }
        else          v = (e == EMB) ? 1.f : 0.f;
        xe[idx] = (f16)v;
    }
}

__global__ void zero_kernel(uint32_t* __restrict__ p, int n)
{
    for (int i = blockIdx.x * blockDim.x + threadIdx.x; i < n; i += gridDim.x * blockDim.x)
        p[i] = 0u;
}

// ---------------------------------------------------------------------------
// One recurrent step GEMM. Z[m][n] = sum_k Aext[m][k] * W[n][k]
//   Aext: k<1024 from A1 (stride 1024), k>=1024 from A2=xe_t (stride 320)
// MODE 0 (gates, N=2048): n<1024 -> RC = sigmoid(z)*c_prev (f16); else U = sigmoid(z) (f32)
// MODE 1 (update, N=1024): cct=tanh(z); Cnext = u*cct + (1-u)*c_prev (f16)
// Block = 256 thr (4 waves); WG tile 64m x 64n; wave = 16m strip x 64n.
// Fragments loaded directly from global (L2-resident weights) — no LDS, no barriers.
// ---------------------------------------------------------------------------
template <int MODE>
__global__ __launch_bounds__(256) void step_kernel(
    const f16* __restrict__ A1, const f16* __restrict__ A2,
    const f16* __restrict__ W,  const f16* __restrict__ Cprev,
    float* __restrict__ U, f16* __restrict__ RC, f16* __restrict__ Cnext)
{
    const int lane = threadIdx.x & 63;
    const int wv   = threadIdx.x >> 6;
    const int q    = lane >> 4;
    const int cx   = lane & 15;
    const int m0   = blockIdx.y * 64 + wv * 16;
    const int n0   = blockIdx.x * 64;
    const int ko   = q * 8;

    const f16* a1 = A1 + (size_t)(m0 + cx) * HID;
    const f16* a2 = A2 + (size_t)(m0 + cx) * XP;
    const f16* b0 = W  + (size_t)(n0 + cx) * KE;

    f32x4 acc[4] = { {0.f,0.f,0.f,0.f}, {0.f,0.f,0.f,0.f},
                     {0.f,0.f,0.f,0.f}, {0.f,0.f,0.f,0.f} };

    #pragma unroll 4
    for (int kc = 0; kc < 32; ++kc) {               // c_prev part of K
        f16x8 a = *(const f16x8*)(a1 + kc * 32 + ko);
        #pragma unroll
        for (int nt = 0; nt < 4; ++nt) {
            f16x8 b = *(const f16x8*)(b0 + (size_t)nt * 16 * KE + kc * 32 + ko);
            acc[nt] = __builtin_amdgcn_mfma_f32_16x16x32_f16(a, b, acc[nt], 0, 0, 0);
        }
    }
    #pragma unroll 2
    for (int kc = 0; kc < 10; ++kc) {               // x part of K (incl. bias-1 col)
        f16x8 a = *(const f16x8*)(a2 + kc * 32 + ko);
        #pragma unroll
        for (int nt = 0; nt < 4; ++nt) {
            f16x8 b = *(const f16x8*)(b0 + (size_t)nt * 16 * KE + 1024 + kc * 32 + ko);
            acc[nt] = __builtin_amdgcn_mfma_f32_16x16x32_f16(a, b, acc[nt], 0, 0, 0);
        }
    }

    // D frag mapping (verified, dtype-independent): col = lane&15, row = (lane>>4)*4 + reg
    #pragma unroll
    for (int nt = 0; nt < 4; ++nt) {
        int n = n0 + nt * 16 + cx;
        #pragma unroll
        for (int r = 0; r < 4; ++r) {
            int m = m0 + q * 4 + r;
            float z = acc[nt][r];
            if (MODE == 0) {
                float s = sigm(z);
                if (n < HID) {
                    float c = (float)Cprev[(size_t)m * HID + n];
                    RC[(size_t)m * HID + n] = (f16)(s * c);
                } else {
                    U[(size_t)m * HID + (n - HID)] = s;
                }
            } else {
                float cct = tanhf_(z);
                float u = U[(size_t)m * HID + n];
                float c = (float)Cprev[(size_t)m * HID + n];
                Cnext[(size_t)m * HID + n] = (f16)(u * cct + (1.f - u) * c);
            }
        }
    }
}

// ---------------------------------------------------------------------------
// Prediction: out[b][t][o] = C_all[t+1][b][:] . Wp[o][:] + bp[o]
// One wave per 16 bt-rows; N padded to 32 (2 n-subtiles), K = 1024.
// ---------------------------------------------------------------------------
__global__ __launch_bounds__(256) void pred_kernel(
    const f16* __restrict__ Call, const f16* __restrict__ Wp,
    const float* __restrict__ bp, float* __restrict__ out)
{
    const int lane = threadIdx.x & 63;
    const int wv   = threadIdx.x >> 6;
    const int q    = lane >> 4, cx = lane & 15;
    const int mt   = blockIdx.x * 4 + wv;            // 0..2047 (bt tile of 16)
    const int ko   = q * 8;
    const f16* ap  = Call + (size_t)(256 + mt * 16 + cx) * HID;   // slot t+1, row b

    f32x4 acc[2] = { {0.f,0.f,0.f,0.f}, {0.f,0.f,0.f,0.f} };
    #pragma unroll 4
    for (int kc = 0; kc < 32; ++kc) {
        f16x8 a = *(const f16x8*)(ap + kc * 32 + ko);
        #pragma unroll
        for (int nt = 0; nt < 2; ++nt) {
            f16x8 b = *(const f16x8*)(Wp + (size_t)(nt * 16 + cx) * HID + kc * 32 + ko);
            acc[nt] = __builtin_amdgcn_mfma_f32_16x16x32_f16(a, b, acc[nt], 0, 0, 0);
        }
    }
    #pragma unroll
    for (int nt = 0; nt < 2; ++nt) {
        int o = nt * 16 + cx;
        if (o < OUTD) {
            #pragma unroll
            for (int r = 0; r < 4; ++r) {
                int bt = mt * 16 + q * 4 + r;        // t*256 + b
                int t  = bt >> 8;
                int b  = bt & 255;
                out[((size_t)b * SEQ + t) * OUTD + o] = acc[nt][r] + bp[o];
            }
        }
    }
}

// ---------------------------------------------------------------------------
extern "C" void kernel_launch(void* const* d_in, const int* in_sizes, int n_in,
                              void* d_out, int out_size, void* d_ws, size_t ws_size,
                              hipStream_t stream)
{
    const int*   x   = (const int*)  d_in[0];
    const float* emb = (const float*)d_in[1];
    const float* Wr  = (const float*)d_in[2];
    const float* br  = (const float*)d_in[3];
    const float* Wu  = (const float*)d_in[4];
    const float* bu  = (const float*)d_in[5];
    const float* Wc  = (const float*)d_in[6];
    const float* bc  = (const float*)d_in[7];
    const float* Wp  = (const float*)d_in[8];
    const float* bp  = (const float*)d_in[9];

    char* p = (char*)d_ws;
    f16* Wru_e = (f16*)p;  p += (size_t)2048 * KE * 2;
    f16* Wc_e  = (f16*)p;  p += (size_t)1024 * KE * 2;
    f16* Wp_e  = (f16*)p;  p += (size_t)32 * HID * 2;
    f16* xe    = (f16*)p;  p += (size_t)SEQ * BATCH * XP * 2;
    f16* Call  = (f16*)p;  p += (size_t)(SEQ + 1) * BATCH * HID * 2;  // slot 0 = zeros
    float* U   = (float*)p; p += (size_t)BATCH * HID * 4;
    f16* RC    = (f16*)p;  p += (size_t)BATCH * HID * 2;

    pack_kernel<<<2048, 256, 0, stream>>>(Wr, br, Wu, bu, Wc, bc, Wp, Wru_e, Wc_e, Wp_e);
    gather_kernel<<<4096, 256, 0, stream>>>(x, emb, xe);
    zero_kernel<<<256, 256, 0, stream>>>((uint32_t*)Call, BATCH * HID / 2);

    for (int t = 0; t < SEQ; ++t) {
        const f16* xet = xe   + (size_t)t * BATCH * XP;
        const f16* Ct  = Call + (size_t)t * BATCH * HID;
        f16* Ct1       = Call + (size_t)(t + 1) * BATCH * HID;
        step_kernel<0><<<dim3(32, 4), 256, 0, stream>>>(Ct, xet, Wru_e, Ct, U, RC, nullptr);
        step_kernel<1><<<dim3(16, 4), 256, 0, stream>>>(RC, xet, Wc_e, Ct, U, nullptr, Ct1);
    }
    pred_kernel<<<512, 256, 0, stream>>>(Call, Wp_e, bp, (float*)d_out);
}